// Round 2
// baseline (212.665 us; speedup 1.0000x reference)
//
#include <hip/hip_runtime.h>
#include <math.h>

#define B 8
#define L 4096
#define D 64
#define TD 128          // 2*D
#define G 64
#define KS 16
#define NSLOT 1024      // G*KS
#define EPS 1e-5f
#define TB 8            // tokens (or slot rows) per block

// ---- workspace layout (float offsets) ----
#define OFF_SSUM 0        // 512
#define OFF_MW0T 512      // 16384  [k][j] 128x128
#define OFF_MW1T 16896    // 8192   [k][j] 128x64
#define OFF_GW0T 25088    // 8192   [k][j] 128x64
#define OFF_WGT  33280    // 8192   [k][g] 128x64
#define OFF_WST  41472    // 2048   [k][s] 128x16
#define OFF_UW0T 43520    // 16384  [k][j] 128x128
#define OFF_UW1T 59904    // 8192   [k][d] 128x64
#define OFF_INC  68096    // 524288 incoming [B][N][D]
// total 592384 floats = ~2.37 MB

__device__ __forceinline__ float gelu_exact(float x) {
    return 0.5f * x * (1.0f + erff(x * 0.70710678118654752f));
}

// ---------------- prep: transposes + state summary ----------------
__global__ __launch_bounds__(256) void prep_kernel(
    const float* __restrict__ S, const float* __restrict__ mw0,
    const float* __restrict__ mw1, const float* __restrict__ gw0,
    const float* __restrict__ Wg, const float* __restrict__ Ws,
    const float* __restrict__ uw0, const float* __restrict__ uw1,
    float* __restrict__ ws)
{
    int blk = blockIdx.x;
    if (blk < 264) {
        int idx = blk * 256 + threadIdx.x;   // [0, 67584)
        if (idx < 16384) {                       // mw0T[k*128+j] = mw0[j*128+k]
            int k = idx >> 7, j = idx & 127;
            ws[OFF_MW0T + idx] = mw0[j * TD + k];
        } else if (idx < 24576) {                // mw1T
            int r = idx - 16384; int k = r >> 6, j = r & 63;
            ws[OFF_MW1T + r] = mw1[j * TD + k];
        } else if (idx < 32768) {                // gw0T
            int r = idx - 24576; int k = r >> 6, j = r & 63;
            ws[OFF_GW0T + r] = gw0[j * TD + k];
        } else if (idx < 40960) {                // WgT
            int r = idx - 32768; int k = r >> 6, j = r & 63;
            ws[OFF_WGT + r] = Wg[j * TD + k];
        } else if (idx < 43008) {                // WsT
            int r = idx - 40960; int k = r >> 4, j = r & 15;
            ws[OFF_WST + r] = Ws[j * TD + k];
        } else if (idx < 59392) {                // uw0T
            int r = idx - 43008; int k = r >> 7, j = r & 127;
            ws[OFF_UW0T + r] = uw0[j * TD + k];
        } else if (idx < 67584) {                // uw1T
            int r = idx - 59392; int k = r >> 6, j = r & 63;
            ws[OFF_UW1T + r] = uw1[j * TD + k];
        }
    } else {
        // state summary: mean over N slots  -> ssum[b][d]
        int b = blk - 264;
        int d = threadIdx.x;
        if (d < D) {
            const float* Sp = S + (size_t)b * NSLOT * D + d;
            float acc = 0.f;
            for (int n = 0; n < NSLOT; ++n) acc += Sp[(size_t)n * D];
            ws[OFF_SSUM + b * D + d] = acc * (1.0f / NSLOT);
        }
    }
}

// ---------------- token kernel: MLPs + routing + scatter ----------------
__global__ __launch_bounds__(128) void token_kernel(
    const float* __restrict__ X,
    const float* __restrict__ mb0, const float* __restrict__ mb1,
    const float* __restrict__ gb0, const float* __restrict__ gw1,
    const float* __restrict__ gb1,
    float* __restrict__ ws)
{
    __shared__ float xs[TD][TB];
    __shared__ float hh[TD][TB];
    __shared__ float msg[D][TB];
    __shared__ float gh[D][TB];
    __shared__ float lg[G][TB];
    __shared__ float ls[KS][TB];
    __shared__ float gate[TB];
    __shared__ int   slot[TB];

    const int t0 = blockIdx.x * TB;      // flat token index base (over B*L)
    const int b  = t0 / L;
    const int l0 = t0 % L;
    const int tid = threadIdx.x;

    // ---- load XS tile: [k][t] layout ----
    for (int idx = tid; idx < TB * D; idx += 128) {
        int t = idx >> 6, d = idx & 63;
        xs[d][t]      = X[((size_t)(b * L + l0 + t)) * D + d];
        xs[d + D][t]  = ws[OFF_SSUM + b * D + d];
    }
    __syncthreads();

    // ---- phase B: H = gelu(XS @ mw0.T + mb0)  (128 hidden) ----
    {
        int j = tid;
        float acc[TB];
        float bias = mb0[j];
        #pragma unroll
        for (int t = 0; t < TB; ++t) acc[t] = bias;
        const float* wp = ws + OFF_MW0T + j;
        #pragma unroll 4
        for (int k = 0; k < TD; ++k) {
            float w = wp[k * TD];
            float4 a = *(const float4*)&xs[k][0];
            float4 c = *(const float4*)&xs[k][4];
            acc[0] += w * a.x; acc[1] += w * a.y; acc[2] += w * a.z; acc[3] += w * a.w;
            acc[4] += w * c.x; acc[5] += w * c.y; acc[6] += w * c.z; acc[7] += w * c.w;
        }
        #pragma unroll
        for (int t = 0; t < TB; ++t) hh[j][t] = gelu_exact(acc[t]);
    }
    __syncthreads();

    // ---- phase C: msg = H @ mw1.T + mb1 ; gate hidden = gelu(XS @ gw0.T + gb0) ----
    {
        float acc[TB];
        if (tid < D) {
            int j = tid;
            float bias = mb1[j];
            #pragma unroll
            for (int t = 0; t < TB; ++t) acc[t] = bias;
            const float* wp = ws + OFF_MW1T + j;
            #pragma unroll 4
            for (int k = 0; k < TD; ++k) {
                float w = wp[k * D];
                float4 a = *(const float4*)&hh[k][0];
                float4 c = *(const float4*)&hh[k][4];
                acc[0] += w * a.x; acc[1] += w * a.y; acc[2] += w * a.z; acc[3] += w * a.w;
                acc[4] += w * c.x; acc[5] += w * c.y; acc[6] += w * c.z; acc[7] += w * c.w;
            }
            #pragma unroll
            for (int t = 0; t < TB; ++t) msg[j][t] = acc[t];
        } else {
            int j = tid - D;
            float bias = gb0[j];
            #pragma unroll
            for (int t = 0; t < TB; ++t) acc[t] = bias;
            const float* wp = ws + OFF_GW0T + j;
            #pragma unroll 4
            for (int k = 0; k < TD; ++k) {
                float w = wp[k * D];
                float4 a = *(const float4*)&xs[k][0];
                float4 c = *(const float4*)&xs[k][4];
                acc[0] += w * a.x; acc[1] += w * a.y; acc[2] += w * a.z; acc[3] += w * a.w;
                acc[4] += w * c.x; acc[5] += w * c.y; acc[6] += w * c.z; acc[7] += w * c.w;
            }
            #pragma unroll
            for (int t = 0; t < TB; ++t) gh[j][t] = gelu_exact(acc[t]);
        }
    }
    __syncthreads();

    // ---- phase D: routing logits (fp32!) + gate scalar ----
    {
        if (tid < G) {                       // group logits
            int g = tid;
            float acc[TB];
            #pragma unroll
            for (int t = 0; t < TB; ++t) acc[t] = 0.f;
            const float* wp = ws + OFF_WGT + g;
            #pragma unroll 4
            for (int k = 0; k < TD; ++k) {
                float w = wp[k * G];
                float4 a = *(const float4*)&xs[k][0];
                float4 c = *(const float4*)&xs[k][4];
                acc[0] += w * a.x; acc[1] += w * a.y; acc[2] += w * a.z; acc[3] += w * a.w;
                acc[4] += w * c.x; acc[5] += w * c.y; acc[6] += w * c.z; acc[7] += w * c.w;
            }
            #pragma unroll
            for (int t = 0; t < TB; ++t) lg[g][t] = acc[t];
        } else if (tid < G + KS) {           // slot logits
            int s = tid - G;
            float acc[TB];
            #pragma unroll
            for (int t = 0; t < TB; ++t) acc[t] = 0.f;
            const float* wp = ws + OFF_WST + s;
            #pragma unroll 4
            for (int k = 0; k < TD; ++k) {
                float w = wp[k * KS];
                float4 a = *(const float4*)&xs[k][0];
                float4 c = *(const float4*)&xs[k][4];
                acc[0] += w * a.x; acc[1] += w * a.y; acc[2] += w * a.z; acc[3] += w * a.w;
                acc[4] += w * c.x; acc[5] += w * c.y; acc[6] += w * c.z; acc[7] += w * c.w;
            }
            #pragma unroll
            for (int t = 0; t < TB; ++t) ls[s][t] = acc[t];
        } else if (tid < G + KS + TB) {      // gate scalar per token
            int t = tid - (G + KS);
            float acc = gb1[0];
            for (int d = 0; d < D; ++d) acc += gw1[d] * gh[d][t];
            gate[t] = 1.0f / (1.0f + expf(-acc));
        }
    }
    __syncthreads();

    // ---- phase E: argmax (first-max semantics) + scatter-add ----
    if (tid < TB) {
        int t = tid;
        int bg = 0; float bv = lg[0][t];
        for (int g = 1; g < G; ++g) { float v = lg[g][t]; if (v > bv) { bv = v; bg = g; } }
        int bs = 0; float sv = ls[0][t];
        for (int s = 1; s < KS; ++s) { float v = ls[s][t]; if (v > sv) { sv = v; bs = s; } }
        slot[t] = bg * KS + bs;
    }
    __syncthreads();

    float* inc = ws + OFF_INC;
    for (int idx = tid; idx < TB * D; idx += 128) {
        int t = idx >> 6, d = idx & 63;
        atomicAdd(&inc[((size_t)(b * NSLOT + slot[t])) * D + d], msg[d][t] * gate[t]);
    }
}

// ---------------- update kernel: slot MLP + residual + layernorm ----------------
__global__ __launch_bounds__(128) void update_kernel(
    const float* __restrict__ S,
    const float* __restrict__ ub0, const float* __restrict__ ub1,
    const float* __restrict__ ln_w, const float* __restrict__ ln_b,
    const float* __restrict__ ws, float* __restrict__ out)
{
    __shared__ float row[TD][TB];
    __shared__ float uu[TD][TB];
    __shared__ float sn[D][TB];
    __shared__ float mu_s[TB], rs_s[TB];

    const int r0 = blockIdx.x * TB;   // flat over B*N
    const int tid = threadIdx.x;

    for (int idx = tid; idx < TB * D; idx += 128) {
        int t = idx >> 6, d = idx & 63;
        size_t g = (size_t)(r0 + t) * D + d;
        row[d][t]     = S[g];
        row[d + D][t] = ws[OFF_INC + g];
    }
    __syncthreads();

    {   // u = gelu(upd_in @ uw0.T + ub0)
        int j = tid;
        float acc[TB];
        float bias = ub0[j];
        #pragma unroll
        for (int t = 0; t < TB; ++t) acc[t] = bias;
        const float* wp = ws + OFF_UW0T + j;
        #pragma unroll 4
        for (int k = 0; k < TD; ++k) {
            float w = wp[k * TD];
            float4 a = *(const float4*)&row[k][0];
            float4 c = *(const float4*)&row[k][4];
            acc[0] += w * a.x; acc[1] += w * a.y; acc[2] += w * a.z; acc[3] += w * a.w;
            acc[4] += w * c.x; acc[5] += w * c.y; acc[6] += w * c.z; acc[7] += w * c.w;
        }
        #pragma unroll
        for (int t = 0; t < TB; ++t) uu[j][t] = gelu_exact(acc[t]);
    }
    __syncthreads();

    if (tid < D) {   // S_new = S + u @ uw1.T + ub1
        int d = tid;
        float acc[TB];
        float bias = ub1[d];
        #pragma unroll
        for (int t = 0; t < TB; ++t) acc[t] = bias;
        const float* wp = ws + OFF_UW1T + d;
        #pragma unroll 4
        for (int k = 0; k < TD; ++k) {
            float w = wp[k * D];
            float4 a = *(const float4*)&uu[k][0];
            float4 c = *(const float4*)&uu[k][4];
            acc[0] += w * a.x; acc[1] += w * a.y; acc[2] += w * a.z; acc[3] += w * a.w;
            acc[4] += w * c.x; acc[5] += w * c.y; acc[6] += w * c.z; acc[7] += w * c.w;
        }
        #pragma unroll
        for (int t = 0; t < TB; ++t) sn[d][t] = S[(size_t)(r0 + t) * D + d] + acc[t];
    }
    __syncthreads();

    if (tid < TB) {   // layernorm stats
        int t = tid;
        float m = 0.f;
        for (int d = 0; d < D; ++d) m += sn[d][t];
        m *= (1.0f / D);
        float v = 0.f;
        for (int d = 0; d < D; ++d) { float dd = sn[d][t] - m; v += dd * dd; }
        v *= (1.0f / D);
        mu_s[t] = m;
        rs_s[t] = rsqrtf(v + EPS);
    }
    __syncthreads();

    for (int idx = tid; idx < TB * D; idx += 128) {
        int t = idx >> 6, d = idx & 63;
        out[(size_t)(r0 + t) * D + d] = (sn[d][t] - mu_s[t]) * rs_s[t] * ln_w[d] + ln_b[d];
    }
}

extern "C" void kernel_launch(void* const* d_in, const int* in_sizes, int n_in,
                              void* d_out, int out_size, void* d_ws, size_t ws_size,
                              hipStream_t stream)
{
    const float* X    = (const float*)d_in[0];
    const float* S    = (const float*)d_in[1];
    const float* Wg   = (const float*)d_in[2];
    const float* Ws   = (const float*)d_in[3];
    const float* mw0  = (const float*)d_in[4];
    const float* mb0  = (const float*)d_in[5];
    const float* mw1  = (const float*)d_in[6];
    const float* mb1  = (const float*)d_in[7];
    const float* gw0  = (const float*)d_in[8];
    const float* gb0  = (const float*)d_in[9];
    const float* gw1  = (const float*)d_in[10];
    const float* gb1  = (const float*)d_in[11];
    const float* uw0  = (const float*)d_in[12];
    const float* ub0  = (const float*)d_in[13];
    const float* uw1  = (const float*)d_in[14];
    const float* ub1  = (const float*)d_in[15];
    const float* ln_w = (const float*)d_in[16];
    const float* ln_b = (const float*)d_in[17];

    float* ws  = (float*)d_ws;
    float* out = (float*)d_out;

    // zero the incoming-accumulator region (ws is poisoned before every call)
    hipMemsetAsync(ws + OFF_INC, 0, (size_t)B * NSLOT * D * sizeof(float), stream);

    prep_kernel<<<272, 256, 0, stream>>>(S, mw0, mw1, gw0, Wg, Ws, uw0, uw1, ws);
    token_kernel<<<(B * L) / TB, 128, 0, stream>>>(X, mb0, mb1, gb0, gw1, gb1, ws);
    update_kernel<<<(B * NSLOT) / TB, 128, 0, stream>>>(S, ub0, ub1, ln_w, ln_b, ws, out);
}

// Round 4
// 182.428 us; speedup vs baseline: 1.1657x; 1.1657x over previous
//
#include <hip/hip_runtime.h>
#include <math.h>

#define B 8
#define L 4096
#define D 64
#define TD 128          // 2*D
#define G 64
#define KS 16
#define NSLOT 1024      // G*KS
#define EPS 1e-5f
#define TB 8

// ---- workspace layout (float offsets) ----
#define OFF_SSUM 0        // 512
#define OFF_WGT  512      // 8192   fp32 [k][g] 128x64
#define OFF_WST  8704     // 2048   fp32 [k][s] 128x16
#define OFF_UW0T 10752    // 16384  fp32 [k][j] 128x128
#define OFF_UW1T 27136    // 8192   fp32 [k][d] 128x64
#define OFF_MW0B 35328    // bf16 16384 elems (8192 floats) — MFMA B-fragment order
#define OFF_MW1B 43520    // bf16 8192  (4096 floats)
#define OFF_GW0B 47616    // bf16 8192  (4096 floats)
#define OFF_SLOT 51712    // 32768 ints
#define OFF_INC  84480    // 524288 floats, incoming [B][N][D]
// total 608768 floats ≈ 2.44 MB

typedef __attribute__((ext_vector_type(8))) short short8;
typedef __attribute__((ext_vector_type(4))) float f32x4;

__device__ __forceinline__ float gelu_exact(float x) {
    return 0.5f * x * (1.0f + erff(x * 0.70710678118654752f));
}

__device__ __forceinline__ unsigned short f2bf(float f) {
    unsigned u = __float_as_uint(f);
    u += 0x7FFFu + ((u >> 16) & 1u);        // round-to-nearest-even
    return (unsigned short)(u >> 16);
}

// ---------------- prep: transposes + bf16 prearrange + state summary ----------------
__global__ __launch_bounds__(256) void prep_kernel(
    const float* __restrict__ S, const float* __restrict__ Wg,
    const float* __restrict__ Ws, const float* __restrict__ mw0,
    const float* __restrict__ mw1, const float* __restrict__ gw0,
    const float* __restrict__ uw0, const float* __restrict__ uw1,
    float* __restrict__ ws)
{
    int blk = blockIdx.x;
    if (blk < 264) {
        int idx = blk * 256 + threadIdx.x;   // [0, 67584)
        unsigned short* wsu = (unsigned short*)ws;
        if (idx < 8192) {                        // WgT fp32 [k][g]
            int k = idx >> 6, g = idx & 63;
            ws[OFF_WGT + idx] = Wg[g * TD + k];
        } else if (idx < 10240) {                // WsT fp32 [k][s]
            int r = idx - 8192; int k = r >> 4, s = r & 15;
            ws[OFF_WST + r] = Ws[s * TD + k];
        } else if (idx < 26624) {                // uw0T fp32
            int r = idx - 10240; int k = r >> 7, j = r & 127;
            ws[OFF_UW0T + r] = uw0[j * TD + k];
        } else if (idx < 34816) {                // uw1T fp32
            int r = idx - 26624; int k = r >> 6, j = r & 63;
            ws[OFF_UW1T + r] = uw1[j * TD + k];
        } else if (idx < 51200) {                // mw0 bf16 B-fragment order
            int r = idx - 34816;
            int e = r & 7, l = (r >> 3) & 63, ks = (r >> 9) & 3, jt = r >> 11;
            int j = jt * 16 + (l & 15); int k = ks * 32 + (l >> 4) * 8 + e;
            wsu[OFF_MW0B * 2 + r] = f2bf(mw0[j * TD + k]);
        } else if (idx < 59392) {                // mw1 bf16
            int r = idx - 51200;
            int e = r & 7, l = (r >> 3) & 63, ks = (r >> 9) & 3, jt = r >> 11;
            int j = jt * 16 + (l & 15); int k = ks * 32 + (l >> 4) * 8 + e;
            wsu[OFF_MW1B * 2 + r] = f2bf(mw1[j * TD + k]);
        } else if (idx < 67584) {                // gw0 bf16
            int r = idx - 59392;
            int e = r & 7, l = (r >> 3) & 63, ks = (r >> 9) & 3, jt = r >> 11;
            int j = jt * 16 + (l & 15); int k = ks * 32 + (l >> 4) * 8 + e;
            wsu[OFF_GW0B * 2 + r] = f2bf(gw0[j * TD + k]);
        }
    } else {
        // state summary — SERIAL add order (bit-identical to baseline; feeds routing)
        int b = blk - 264;
        int d = threadIdx.x;
        if (d < D) {
            const float* Sp = S + (size_t)b * NSLOT * D + d;
            float acc = 0.f;
            for (int n0 = 0; n0 < NSLOT; n0 += 16) {
                float v[16];
                #pragma unroll
                for (int u = 0; u < 16; ++u) v[u] = Sp[(size_t)(n0 + u) * D];
                #pragma unroll
                for (int u = 0; u < 16; ++u) acc += v[u];
            }
            ws[OFF_SSUM + b * D + d] = acc * (1.0f / NSLOT);
        }
    }
}

// ---------------- routing: fp32 logits (bit-identical to baseline) + argmax ----------------
__global__ __launch_bounds__(256) void routing_kernel(
    const float* __restrict__ X, float* __restrict__ ws)
{
    __shared__ float xs[2][TD][TB];
    __shared__ float lg[2][G][TB];
    __shared__ float ls[2][KS][TB];

    const int half = threadIdx.x >> 7;
    const int tid  = threadIdx.x & 127;
    const int t0 = blockIdx.x * 16 + half * TB;   // flat token base
    const int b  = t0 / L;
    const int l0 = t0 % L;

    // ---- phase A: load XS tile [k][t] (identical values/layout to baseline) ----
    for (int idx = tid; idx < TB * D; idx += 128) {
        int t = idx >> 6, d = idx & 63;
        xs[half][d][t]     = X[((size_t)(b * L + l0 + t)) * D + d];
        xs[half][d + D][t] = ws[OFF_SSUM + b * D + d];
    }
    __syncthreads();

    // ---- phase D: routing logits — VERBATIM arithmetic from baseline ----
    {
        if (tid < G) {
            int g = tid;
            float acc[TB];
            #pragma unroll
            for (int t = 0; t < TB; ++t) acc[t] = 0.f;
            const float* wp = ws + OFF_WGT + g;
            #pragma unroll 4
            for (int k = 0; k < TD; ++k) {
                float w = wp[k * G];
                float4 a = *(const float4*)&xs[half][k][0];
                float4 c = *(const float4*)&xs[half][k][4];
                acc[0] += w * a.x; acc[1] += w * a.y; acc[2] += w * a.z; acc[3] += w * a.w;
                acc[4] += w * c.x; acc[5] += w * c.y; acc[6] += w * c.z; acc[7] += w * c.w;
            }
            #pragma unroll
            for (int t = 0; t < TB; ++t) lg[half][g][t] = acc[t];
        } else if (tid < G + KS) {
            int s = tid - G;
            float acc[TB];
            #pragma unroll
            for (int t = 0; t < TB; ++t) acc[t] = 0.f;
            const float* wp = ws + OFF_WST + s;
            #pragma unroll 4
            for (int k = 0; k < TD; ++k) {
                float w = wp[k * KS];
                float4 a = *(const float4*)&xs[half][k][0];
                float4 c = *(const float4*)&xs[half][k][4];
                acc[0] += w * a.x; acc[1] += w * a.y; acc[2] += w * a.z; acc[3] += w * a.w;
                acc[4] += w * c.x; acc[5] += w * c.y; acc[6] += w * c.z; acc[7] += w * c.w;
            }
            #pragma unroll
            for (int t = 0; t < TB; ++t) ls[half][s][t] = acc[t];
        }
    }
    __syncthreads();

    // ---- phase E: argmax (first-max semantics, verbatim) → slot to global ----
    if (tid < TB) {
        int t = tid;
        int bg = 0; float bv = lg[half][0][t];
        for (int g = 1; g < G; ++g) { float v = lg[half][g][t]; if (v > bv) { bv = v; bg = g; } }
        int bs = 0; float sv = ls[half][0][t];
        for (int s = 1; s < KS; ++s) { float v = ls[half][s][t]; if (v > sv) { sv = v; bs = s; } }
        ((int*)(ws + OFF_SLOT))[t0 + t] = bg * KS + bs;
    }
}

// ---------------- msg kernel: bf16 MFMA MLPs + gate + scatter ----------------
__global__ __launch_bounds__(256) void msg_kernel(
    const float* __restrict__ X,
    const float* __restrict__ mb0, const float* __restrict__ mb1,
    const float* __restrict__ gb0, const float* __restrict__ gw1,
    const float* __restrict__ gb1, float* __restrict__ ws)
{
    // padded stride 136 bf16 elems (272 B) -> 2-way (free) LDS conflicts on frag reads
    __shared__ __align__(16) unsigned short xsl[64 * 136];
    __shared__ __align__(16) unsigned short hhl[64 * 136];
    __shared__ float msgl[64 * 68];
    __shared__ float ghl[64 * 68];
    __shared__ float gatel[64];
    __shared__ int   slotl[64];

    const int tid  = threadIdx.x;
    const int tok0 = blockIdx.x * 64;
    const int b    = tok0 >> 12;      // / L

    if (tid < 64) slotl[tid] = ((const int*)(ws + OFF_SLOT))[tok0 + tid];

    // ---- stage XS as bf16 ----
    {
        int t = tid >> 2, q = tid & 3;
        unsigned short tmp[32];
        if (q < 2) {
            const float* Xp = X + (size_t)(tok0 + t) * D + q * 32;
            #pragma unroll
            for (int u = 0; u < 8; ++u) {
                float4 v = *(const float4*)(Xp + u * 4);
                tmp[u*4+0] = f2bf(v.x); tmp[u*4+1] = f2bf(v.y);
                tmp[u*4+2] = f2bf(v.z); tmp[u*4+3] = f2bf(v.w);
            }
        } else {
            const float* Sp = ws + OFF_SSUM + b * D + (q - 2) * 32;
            #pragma unroll
            for (int u = 0; u < 32; ++u) tmp[u] = f2bf(Sp[u]);
        }
        #pragma unroll
        for (int s = 0; s < 4; ++s)
            *(short8*)&xsl[t * 136 + (q * 4 + s) * 8] = *(const short8*)&tmp[s * 8];
    }
    __syncthreads();

    const int w  = tid >> 6;
    const int l  = tid & 63;
    const int lr = l & 15;
    const int lk = l >> 4;
    const unsigned short* wsu = (const unsigned short*)ws;

    // ---- GEMM1: H = gelu(XS @ mw0^T + mb0), wave w owns cols [w*32, w*32+32) ----
    {
        f32x4 acc[2][4];
        #pragma unroll
        for (int a_ = 0; a_ < 2; ++a_)
            #pragma unroll
            for (int b_ = 0; b_ < 4; ++b_) acc[a_][b_] = (f32x4){0.f, 0.f, 0.f, 0.f};

        for (int ks = 0; ks < 4; ++ks) {
            short8 a[4];
            #pragma unroll
            for (int tt = 0; tt < 4; ++tt)
                a[tt] = *(const short8*)&xsl[(tt * 16 + lr) * 136 + (ks * 4 + lk) * 8];
            #pragma unroll
            for (int jt2 = 0; jt2 < 2; ++jt2) {
                int jt = w * 2 + jt2;
                short8 bb = *(const short8*)&wsu[OFF_MW0B * 2 + ((jt * 4 + ks) * 64 + l) * 8];
                #pragma unroll
                for (int tt = 0; tt < 4; ++tt)
                    acc[jt2][tt] = __builtin_amdgcn_mfma_f32_16x16x32_bf16(a[tt], bb, acc[jt2][tt], 0, 0, 0);
            }
        }
        #pragma unroll
        for (int jt2 = 0; jt2 < 2; ++jt2) {
            int j = w * 32 + jt2 * 16 + lr;
            float bias = mb0[j];
            #pragma unroll
            for (int tt = 0; tt < 4; ++tt) {
                #pragma unroll
                for (int r = 0; r < 4; ++r) {
                    int t = tt * 16 + lk * 4 + r;
                    hhl[t * 136 + j] = f2bf(gelu_exact(acc[jt2][tt][r] + bias));
                }
            }
        }
    }
    __syncthreads();

    // ---- GEMM2: waves 0,1: msg = H @ mw1^T + mb1 ; waves 2,3: gh = gelu(XS @ gw0^T + gb0) ----
    {
        f32x4 acc[2][4];
        #pragma unroll
        for (int a_ = 0; a_ < 2; ++a_)
            #pragma unroll
            for (int b_ = 0; b_ < 4; ++b_) acc[a_][b_] = (f32x4){0.f, 0.f, 0.f, 0.f};

        const unsigned short* srcA = (w < 2) ? hhl : xsl;
        const int wb   = (w < 2) ? w : (w - 2);
        const int boff = (w < 2) ? OFF_MW1B * 2 : OFF_GW0B * 2;

        for (int ks = 0; ks < 4; ++ks) {
            short8 a[4];
            #pragma unroll
            for (int tt = 0; tt < 4; ++tt)
                a[tt] = *(const short8*)&srcA[(tt * 16 + lr) * 136 + (ks * 4 + lk) * 8];
            #pragma unroll
            for (int jt2 = 0; jt2 < 2; ++jt2) {
                int jt = wb * 2 + jt2;
                short8 bb = *(const short8*)&wsu[boff + ((jt * 4 + ks) * 64 + l) * 8];
                #pragma unroll
                for (int tt = 0; tt < 4; ++tt)
                    acc[jt2][tt] = __builtin_amdgcn_mfma_f32_16x16x32_bf16(a[tt], bb, acc[jt2][tt], 0, 0, 0);
            }
        }
        if (w < 2) {
            #pragma unroll
            for (int jt2 = 0; jt2 < 2; ++jt2) {
                int j = w * 32 + jt2 * 16 + lr;
                float bias = mb1[j];
                #pragma unroll
                for (int tt = 0; tt < 4; ++tt)
                    #pragma unroll
                    for (int r = 0; r < 4; ++r) {
                        int t = tt * 16 + lk * 4 + r;
                        msgl[t * 68 + j] = acc[jt2][tt][r] + bias;
                    }
            }
        } else {
            #pragma unroll
            for (int jt2 = 0; jt2 < 2; ++jt2) {
                int j = wb * 32 + jt2 * 16 + lr;
                float bias = gb0[j];
                #pragma unroll
                for (int tt = 0; tt < 4; ++tt)
                    #pragma unroll
                    for (int r = 0; r < 4; ++r) {
                        int t = tt * 16 + lk * 4 + r;
                        ghl[t * 68 + j] = gelu_exact(acc[jt2][tt][r] + bias);
                    }
            }
        }
    }
    __syncthreads();

    // ---- gate scalar per token ----
    if (tid < 64) {
        float acc = gb1[0];
        for (int jj = 0; jj < D; ++jj) acc += ghl[tid * 68 + jj] * gw1[jj];
        gatel[tid] = 1.0f / (1.0f + expf(-acc));
    }
    __syncthreads();

    // ---- scatter gated msg ----
    float* inc = ws + OFF_INC;
    #pragma unroll
    for (int i = tid; i < 64 * D; i += 256) {
        int t = i >> 6, d = i & 63;
        atomicAdd(&inc[((size_t)(b * NSLOT + slotl[t])) * D + d], msgl[t * 68 + d] * gatel[t]);
    }
}

// ---------------- update kernel: split-k slot MLP + residual + layernorm ----------------
__global__ __launch_bounds__(256) void update_kernel(
    const float* __restrict__ S,
    const float* __restrict__ ub0, const float* __restrict__ ub1,
    const float* __restrict__ ln_w, const float* __restrict__ ln_b,
    const float* __restrict__ ws, float* __restrict__ out)
{
    __shared__ float row[TD][TB];
    __shared__ float pb[2][TD][TB];
    __shared__ float uu[TD][TB];
    __shared__ float pc[4][D][TB];
    __shared__ float sn[D][TB];
    __shared__ float mu_s[TB], rs_s[TB];

    const int r0 = blockIdx.x * TB;
    const int tid = threadIdx.x;

    for (int idx = tid; idx < TB * D; idx += 256) {
        int t = idx >> 6, d = idx & 63;
        size_t g = (size_t)(r0 + t) * D + d;
        row[d][t]     = S[g];
        row[d + D][t] = ws[OFF_INC + g];
    }
    __syncthreads();

    {   // phase B: 2-way split-k over uw0
        int j = tid & 127, kh = tid >> 7;
        float acc[TB];
        #pragma unroll
        for (int t = 0; t < TB; ++t) acc[t] = 0.f;
        const float* wp = ws + OFF_UW0T + (size_t)kh * 64 * TD + j;
        #pragma unroll 4
        for (int k = 0; k < 64; ++k) {
            float w = wp[k * TD];
            float4 a = *(const float4*)&row[kh * 64 + k][0];
            float4 c = *(const float4*)&row[kh * 64 + k][4];
            acc[0] += w * a.x; acc[1] += w * a.y; acc[2] += w * a.z; acc[3] += w * a.w;
            acc[4] += w * c.x; acc[5] += w * c.y; acc[6] += w * c.z; acc[7] += w * c.w;
        }
        #pragma unroll
        for (int t = 0; t < TB; ++t) pb[kh][j][t] = acc[t];
    }
    __syncthreads();
    for (int idx = tid; idx < TD * TB; idx += 256) {
        int j = idx >> 3, t = idx & 7;
        uu[j][t] = gelu_exact(pb[0][j][t] + pb[1][j][t] + ub0[j]);
    }
    __syncthreads();

    {   // phase C: 4-way split-k over uw1
        int d = tid & 63, kq = tid >> 6;
        float acc[TB];
        #pragma unroll
        for (int t = 0; t < TB; ++t) acc[t] = 0.f;
        const float* wp = ws + OFF_UW1T + (size_t)kq * 32 * D + d;
        #pragma unroll 4
        for (int k = 0; k < 32; ++k) {
            float w = wp[k * D];
            float4 a = *(const float4*)&uu[kq * 32 + k][0];
            float4 c = *(const float4*)&uu[kq * 32 + k][4];
            acc[0] += w * a.x; acc[1] += w * a.y; acc[2] += w * a.z; acc[3] += w * a.w;
            acc[4] += w * c.x; acc[5] += w * c.y; acc[6] += w * c.z; acc[7] += w * c.w;
        }
        #pragma unroll
        for (int t = 0; t < TB; ++t) pc[kq][d][t] = acc[t];
    }
    __syncthreads();
    for (int idx = tid; idx < D * TB; idx += 256) {
        int d = idx >> 3, t = idx & 7;
        sn[d][t] = S[(size_t)(r0 + t) * D + d] + ub1[d]
                 + pc[0][d][t] + pc[1][d][t] + pc[2][d][t] + pc[3][d][t];
    }
    __syncthreads();

    if (tid < TB) {
        int t = tid;
        float m = 0.f;
        for (int d = 0; d < D; ++d) m += sn[d][t];
        m *= (1.0f / D);
        float v = 0.f;
        for (int d = 0; d < D; ++d) { float dd = sn[d][t] - m; v += dd * dd; }
        v *= (1.0f / D);
        mu_s[t] = m;
        rs_s[t] = rsqrtf(v + EPS);
    }
    __syncthreads();

    for (int idx = tid; idx < TB * D; idx += 256) {
        int t = idx >> 6, d = idx & 63;
        out[(size_t)(r0 + t) * D + d] = (sn[d][t] - mu_s[t]) * rs_s[t] * ln_w[d] + ln_b[d];
    }
}

extern "C" void kernel_launch(void* const* d_in, const int* in_sizes, int n_in,
                              void* d_out, int out_size, void* d_ws, size_t ws_size,
                              hipStream_t stream)
{
    const float* X    = (const float*)d_in[0];
    const float* S    = (const float*)d_in[1];
    const float* Wg   = (const float*)d_in[2];
    const float* Ws   = (const float*)d_in[3];
    const float* mw0  = (const float*)d_in[4];
    const float* mb0  = (const float*)d_in[5];
    const float* mw1  = (const float*)d_in[6];
    const float* mb1  = (const float*)d_in[7];
    const float* gw0  = (const float*)d_in[8];
    const float* gb0  = (const float*)d_in[9];
    const float* gw1  = (const float*)d_in[10];
    const float* gb1  = (const float*)d_in[11];
    const float* uw0  = (const float*)d_in[12];
    const float* ub0  = (const float*)d_in[13];
    const float* uw1  = (const float*)d_in[14];
    const float* ub1  = (const float*)d_in[15];
    const float* ln_w = (const float*)d_in[16];
    const float* ln_b = (const float*)d_in[17];

    float* ws  = (float*)d_ws;
    float* out = (float*)d_out;

    hipMemsetAsync(ws + OFF_INC, 0, (size_t)B * NSLOT * D * sizeof(float), stream);

    prep_kernel<<<272, 256, 0, stream>>>(S, Wg, Ws, mw0, mw1, gw0, uw0, uw1, ws);
    routing_kernel<<<(B * L) / 16, 256, 0, stream>>>(X, ws);
    msg_kernel<<<(B * L) / 64, 256, 0, stream>>>(X, mb0, mb1, gb0, gw1, gb1, ws);
    update_kernel<<<(B * NSLOT) / TB, 256, 0, stream>>>(S, ub0, ub1, ln_w, ln_b, ws, out);
}